// Round 1
// baseline (220.129 us; speedup 1.0000x reference)
//
#include <hip/hip_runtime.h>

typedef unsigned long long ull;

#define N_PTS   1000000
#define DM      128
#define DP      64
#define RNB     32
#define ENT     32
#define EFS     64
#define KOUT    10
#define N_ITERS 8
#define NTH     512
#define MAXSORT 4096
#define BIGF    1e30f
#define PADKEY  0xFFFFFFFFFFFFFFFFull

__device__ __forceinline__ unsigned fkey_enc(float d) {
  unsigned b = __float_as_uint(d);
  return (b & 0x80000000u) ? ~b : (b | 0x80000000u);
}

// Distance in principal subspace (first 64 dims). Single definition with a
// fixed accumulation order => any given id always yields the bit-identical
// distance, so duplicate ids have identical (dist,id) keys and dedup after
// sort is just "drop element equal to predecessor".
__device__ __forceinline__ float dist_p(const float* __restrict__ storage,
                                        const float* qf, float qn, int id) {
  int c = id < 0 ? 0 : (id > N_PTS - 1 ? N_PTS - 1 : id);
  const float4* row = (const float4*)(storage + (size_t)c * DM);
  float sq = 0.f, dt = 0.f;
#pragma unroll
  for (int j = 0; j < DP / 4; ++j) {
    float4 s = row[j];
    sq = fmaf(s.x, s.x, sq); sq = fmaf(s.y, s.y, sq);
    sq = fmaf(s.z, s.z, sq); sq = fmaf(s.w, s.w, sq);
    dt = fmaf(s.x, qf[4*j+0], dt); dt = fmaf(s.y, qf[4*j+1], dt);
    dt = fmaf(s.z, qf[4*j+2], dt); dt = fmaf(s.w, qf[4*j+3], dt);
  }
  float d = sq - 2.f * dt + qn;
  return (id >= N_PTS) ? BIGF : d;
}

// In-LDS bitonic sort of keys[0..m), m a power of two. Callers sync before.
__device__ void bitonic_sort(ull* keys, int m, int tid) {
  for (int k = 2; k <= m; k <<= 1) {
    for (int j = k >> 1; j > 0; j >>= 1) {
      for (int i = tid; i < m; i += NTH) {
        int ixj = i ^ j;
        if (ixj > i) {
          ull a = keys[i], b = keys[ixj];
          bool up = ((i & k) == 0);
          if ((a > b) == up) { keys[i] = b; keys[ixj] = a; }
        }
      }
      __syncthreads();
    }
  }
}

// keys[0..m) sorted ascending. Write first EFS distinct (non-PAD) keys into
// beamkey, fill remainder with (BIG, n), unpack ids. Chunked block scan.
__device__ void dedup_compact(ull* keys, int m, ull* beamkey, int* beam_id,
                              int* scanpart, int tid) {
  int C = (m + NTH - 1) / NTH;
  int base = tid * C;
  int lim = base + C; if (lim > m) lim = m;
  int lc = 0;
  for (int i = base; i < lim; ++i) {
    ull ki = keys[i];
    bool v = (ki != PADKEY) && (i == 0 || ki != keys[i - 1]);
    lc += (int)v;
  }
  scanpart[tid] = lc;
  __syncthreads();
  for (int off = 1; off < NTH; off <<= 1) {
    int v = scanpart[tid];
    int add = (tid >= off) ? scanpart[tid - off] : 0;
    __syncthreads();
    scanpart[tid] = v + add;
    __syncthreads();
  }
  int rank = scanpart[tid] - lc;       // exclusive prefix for this chunk
  int T = scanpart[NTH - 1];           // total distinct
  for (int i = base; i < lim; ++i) {
    ull ki = keys[i];
    bool v = (ki != PADKEY) && (i == 0 || ki != keys[i - 1]);
    if (v) { if (rank < EFS) beamkey[rank] = ki; rank++; }
  }
  ull fillkey = ((ull)fkey_enc(BIGF) << 32) | (unsigned)N_PTS;
  int Tc = T < EFS ? T : EFS;
  for (int i = Tc + tid; i < EFS; i += NTH) beamkey[i] = fillkey;
  __syncthreads();
  if (tid < EFS) beam_id[tid] = (int)(beamkey[tid] & 0xFFFFFFFFull);
  __syncthreads();
}

__global__ __launch_bounds__(NTH) void search_kernel(
    const float* __restrict__ query,     // B x 128
    const float* __restrict__ VT,        // 128 x 128
    const float* __restrict__ storage,   // N x 128
    const int*   __restrict__ neighbors, // N x 32
    const int*   __restrict__ entry_ids, // 32
    float* __restrict__ out)             // [B*K ids | B*K dists] as float32
{
  __shared__ ull   keys[MAXSORT];
  __shared__ ull   beamkey[EFS];
  __shared__ int   beam_id[EFS];
  __shared__ float qf[DM];
  __shared__ float qloc[DM];
  __shared__ float qn_s;
  __shared__ int   cnt;
  __shared__ int   scanpart[NTH];
  __shared__ float dfull[EFS];

  const int b   = blockIdx.x;
  const int B   = gridDim.x;
  const int tid = threadIdx.x;

  // ---- q_full = query[b] @ VT.T ----
  if (tid < DM) qloc[tid] = query[(size_t)b * DM + tid];
  __syncthreads();
  if (tid < DM) {
    const float* vrow = VT + (size_t)tid * DM;
    float acc = 0.f;
#pragma unroll 8
    for (int d = 0; d < DM; ++d) acc = fmaf(qloc[d], vrow[d], acc);
    qf[tid] = acc;
  }
  __syncthreads();
  if (tid == 0) {
    float acc = 0.f;
    for (int d = 0; d < DP; ++d) acc = fmaf(qf[d], qf[d], acc);
    qn_s = acc;
  }
  __syncthreads();
  const float qn = qn_s;

  // ---- entry stage: 32 entries + 32 (BIG, n) pads -> sorted distinct beam ----
  if (tid < ENT) {
    int id = entry_ids[tid];
    float d = dist_p(storage, qf, qn, id);
    keys[tid] = ((ull)fkey_enc(d) << 32) | (unsigned)id;
  } else if (tid < EFS) {
    keys[tid] = ((ull)fkey_enc(BIGF) << 32) | (unsigned)N_PTS;
  }
  __syncthreads();
  bitonic_sort(keys, EFS, tid);
  dedup_compact(keys, EFS, beamkey, beam_id, scanpart, tid);

  // ---- 8 search iterations ----
  for (int it = 0; it < N_ITERS; ++it) {
    ull kmax = beamkey[EFS - 1];
    if (tid < EFS) keys[tid] = beamkey[tid];
    if (tid == 0) cnt = EFS;
    __syncthreads();

    // expand beam: 64 x 32 candidates, filter against beam max key
    for (int ci = tid; ci < EFS * RNB; ci += NTH) {
      int e = ci >> 5;
      int r = ci & 31;
      int bid = beam_id[e];
      int cid = (bid >= N_PTS) ? N_PTS : neighbors[(size_t)bid * RNB + r];
      float d = dist_p(storage, qf, qn, cid);
      ull key = ((ull)fkey_enc(d) << 32) | (unsigned)cid;
      if (key < kmax) {
        int p = atomicAdd(&cnt, 1);
        keys[p] = key;
      }
    }
    __syncthreads();

    int count = cnt;
    int m = EFS;
    while (m < count) m <<= 1;  // next pow2, <= 4096 (count <= 2112)
    for (int i = count + tid; i < m; i += NTH) keys[i] = PADKEY;
    __syncthreads();

    bitonic_sort(keys, m, tid);
    dedup_compact(keys, m, beamkey, beam_id, scanpart, tid);
  }

  // ---- final: full 128-dim distances, top-k by (d_full, beam position) ----
  if (tid < EFS) {
    int id = beam_id[tid];
    int c = id < 0 ? 0 : (id > N_PTS - 1 ? N_PTS - 1 : id);
    const float4* row = (const float4*)(storage + (size_t)c * DM);
    float acc = 0.f;
#pragma unroll
    for (int j = 0; j < DM / 4; ++j) {
      float4 s = row[j];
      float dx = s.x - qf[4*j+0]; acc = fmaf(dx, dx, acc);
      dx = s.y - qf[4*j+1]; acc = fmaf(dx, dx, acc);
      dx = s.z - qf[4*j+2]; acc = fmaf(dx, dx, acc);
      dx = s.w - qf[4*j+3]; acc = fmaf(dx, dx, acc);
    }
    float dv = (id >= N_PTS) ? BIGF : acc;
    dfull[tid] = dv;
    keys[tid] = ((ull)fkey_enc(dv) << 32) | (unsigned)tid;  // tie-break: position
  }
  __syncthreads();
  bitonic_sort(keys, EFS, tid);
  if (tid < KOUT) {
    int pos = (int)(keys[tid] & 0xFFFFFFFFull);
    out[(size_t)b * KOUT + tid] = (float)beam_id[pos];
    out[(size_t)B * KOUT + (size_t)b * KOUT + tid] = dfull[pos];
  }
}

extern "C" void kernel_launch(void* const* d_in, const int* in_sizes, int n_in,
                              void* d_out, int out_size, void* d_ws, size_t ws_size,
                              hipStream_t stream) {
  const float* query     = (const float*)d_in[0];
  const float* VT        = (const float*)d_in[1];
  const float* storage   = (const float*)d_in[2];
  const int*   neighbors = (const int*)d_in[3];
  const int*   entry_ids = (const int*)d_in[4];
  float* out = (float*)d_out;

  int B = in_sizes[0] / DM;  // 128
  search_kernel<<<B, NTH, 0, stream>>>(query, VT, storage, neighbors, entry_ids, out);
}

// Round 2
// 178.745 us; speedup vs baseline: 1.2315x; 1.2315x over previous
//
#include <hip/hip_runtime.h>

typedef unsigned long long ull;

#define N_PTS   1000000
#define DM      128
#define DP      64
#define RNB     32
#define ENT     32
#define EFS     64
#define KOUT    10
#define N_ITERS 8
#define NTH     512
#define MAXSORT 4096
#define HASHCAP 16384
#define PROBE_MAX 128
#define MAXEVAL (EFS * RNB + 64)
#define BIGF    1e30f
#define PADKEY  0xFFFFFFFFFFFFFFFFull

__device__ __forceinline__ unsigned fkey_enc(float d) {
  unsigned b = __float_as_uint(d);
  return (b & 0x80000000u) ? ~b : (b | 0x80000000u);
}

// Distance in principal subspace (first 64 dims). Fixed accumulation order =>
// a given id always yields bit-identical distance (dup keys identical).
// KEEP BIT-IDENTICAL to round-0 version (absmax was 0.0).
__device__ __forceinline__ float dist_p(const float* __restrict__ storage,
                                        const float* qf, float qn, int id) {
  int c = id < 0 ? 0 : (id > N_PTS - 1 ? N_PTS - 1 : id);
  const float4* row = (const float4*)(storage + (size_t)c * DM);
  float sq = 0.f, dt = 0.f;
#pragma unroll
  for (int j = 0; j < DP / 4; ++j) {
    float4 s = row[j];
    sq = fmaf(s.x, s.x, sq); sq = fmaf(s.y, s.y, sq);
    sq = fmaf(s.z, s.z, sq); sq = fmaf(s.w, s.w, sq);
    dt = fmaf(s.x, qf[4*j+0], dt); dt = fmaf(s.y, qf[4*j+1], dt);
    dt = fmaf(s.z, qf[4*j+2], dt); dt = fmaf(s.w, qf[4*j+3], dt);
  }
  float d = sq - 2.f * dt + qn;
  return (id >= N_PTS) ? BIGF : d;
}

// Claim id in visited set. Returns true if caller must evaluate it
// (newly claimed, or table too full to decide). Sets *dupflag on overflow.
__device__ __forceinline__ bool visit_claim(int* htab, int id, int* dupflag) {
  unsigned h = ((unsigned)id * 2654435761u) & (HASHCAP - 1);
  for (int p = 0; p < PROBE_MAX; ++p) {
    int cur = htab[h];
    if (cur == id) return false;          // already visited: exact skip
    if (cur == -1) {
      int old = atomicCAS(&htab[h], -1, id);
      if (old == -1) return true;         // claimed: evaluate
      if (old == id) return false;        // lost race to same id: skip
      // slot taken by different id: keep probing
    }
    h = (h + 1) & (HASHCAP - 1);
  }
  atomicExch(dupflag, 1);                 // table saturated: dup possible
  return true;                            // evaluate anyway (dedup catches it)
}

// In-LDS bitonic sort of keys[0..m), m a power of two.
__device__ void bitonic_sort(ull* keys, int m, int tid) {
  for (int k = 2; k <= m; k <<= 1) {
    for (int j = k >> 1; j > 0; j >>= 1) {
      for (int i = tid; i < m; i += NTH) {
        int ixj = i ^ j;
        if (ixj > i) {
          ull a = keys[i], b = keys[ixj];
          bool up = ((i & k) == 0);
          if ((a > b) == up) { keys[i] = b; keys[ixj] = a; }
        }
      }
      __syncthreads();
    }
  }
}

// keys[0..m) sorted ascending, possibly with duplicate/PAD keys. Write first
// EFS distinct keys into beamkey (+fill), unpack ids. Chunked block scan.
__device__ void dedup_compact(ull* keys, int m, ull* beamkey, int* beam_id,
                              int* scanpart, int tid) {
  int C = (m + NTH - 1) / NTH;
  int base = tid * C;
  int lim = base + C; if (lim > m) lim = m;
  int lc = 0;
  for (int i = base; i < lim; ++i) {
    ull ki = keys[i];
    bool v = (ki != PADKEY) && (i == 0 || ki != keys[i - 1]);
    lc += (int)v;
  }
  scanpart[tid] = lc;
  __syncthreads();
  for (int off = 1; off < NTH; off <<= 1) {
    int v = scanpart[tid];
    int add = (tid >= off) ? scanpart[tid - off] : 0;
    __syncthreads();
    scanpart[tid] = v + add;
    __syncthreads();
  }
  int rank = scanpart[tid] - lc;
  int T = scanpart[NTH - 1];
  for (int i = base; i < lim; ++i) {
    ull ki = keys[i];
    bool v = (ki != PADKEY) && (i == 0 || ki != keys[i - 1]);
    if (v) { if (rank < EFS) beamkey[rank] = ki; rank++; }
  }
  ull fillkey = ((ull)fkey_enc(BIGF) << 32) | (unsigned)N_PTS;
  int Tc = T < EFS ? T : EFS;
  for (int i = Tc + tid; i < EFS; i += NTH) beamkey[i] = fillkey;
  __syncthreads();
  if (tid < EFS) beam_id[tid] = (int)(beamkey[tid] & 0xFFFFFFFFull);
  __syncthreads();
}

__global__ __launch_bounds__(NTH) void search_kernel(
    const float* __restrict__ query,     // B x 128
    const float* __restrict__ VT,        // 128 x 128
    const float* __restrict__ storage,   // N x 128
    const int*   __restrict__ neighbors, // N x 32
    const int*   __restrict__ entry_ids, // 32
    float* __restrict__ out)             // [B*K ids | B*K dists] as float32
{
  __shared__ ull   keys[MAXSORT];      // 32 KB
  __shared__ int   htab[HASHCAP];      // 64 KB
  __shared__ int   evalids[MAXEVAL];   // 8.4 KB
  __shared__ ull   beamkey[EFS];
  __shared__ int   beam_id[EFS];
  __shared__ float qf[DM];
  __shared__ float qloc[DM];
  __shared__ float qn_s;
  __shared__ int   cnt, ecnt, dupflag;
  __shared__ int   scanpart[NTH];
  __shared__ float dfull[EFS];

  const int b   = blockIdx.x;
  const int B   = gridDim.x;
  const int tid = threadIdx.x;

  // ---- init visited set ----
  for (int i = tid; i < HASHCAP; i += NTH) htab[i] = -1;
  if (tid == 0) dupflag = 0;

  // ---- q_full = query[b] @ VT.T ----
  if (tid < DM) qloc[tid] = query[(size_t)b * DM + tid];
  __syncthreads();
  if (tid < DM) {
    const float* vrow = VT + (size_t)tid * DM;
    float acc = 0.f;
#pragma unroll 8
    for (int d = 0; d < DM; ++d) acc = fmaf(qloc[d], vrow[d], acc);
    qf[tid] = acc;
  }
  __syncthreads();
  if (tid == 0) {
    float acc = 0.f;
    for (int d = 0; d < DP; ++d) acc = fmaf(qf[d], qf[d], acc);
    qn_s = acc;
  }
  __syncthreads();
  const float qn = qn_s;

  // ---- entry stage (entry_ids may contain dups -> keep full dedup here) ----
  if (tid < ENT) {
    int id = entry_ids[tid];
    visit_claim(htab, id, &dupflag);   // mark visited; dups fine
    float d = dist_p(storage, qf, qn, id);
    keys[tid] = ((ull)fkey_enc(d) << 32) | (unsigned)id;
  } else if (tid < EFS) {
    keys[tid] = ((ull)fkey_enc(BIGF) << 32) | (unsigned)N_PTS;
  }
  __syncthreads();
  bitonic_sort(keys, EFS, tid);
  dedup_compact(keys, EFS, beamkey, beam_id, scanpart, tid);

  // ---- search iterations ----
  for (int it = 0; it < N_ITERS; ++it) {
    ull kmax = beamkey[EFS - 1];
    if (tid < EFS) keys[tid] = beamkey[tid];
    if (tid == 0) { cnt = EFS; ecnt = 0; }
    __syncthreads();

    // phase 1: propose 64x32 neighbor ids, claim unvisited ones
    for (int ci = tid; ci < EFS * RNB; ci += NTH) {
      int e = ci >> 5;
      int r = ci & 31;
      int bid = beam_id[e];
      if (bid >= N_PTS) continue;                 // beam fill slot
      int cid = neighbors[(size_t)bid * RNB + r];
      if (visit_claim(htab, cid, &dupflag)) {
        int p = atomicAdd(&ecnt, 1);
        evalids[p] = cid;
      }
    }
    __syncthreads();

    // phase 2: evaluate claimed candidates, filter vs beam max key
    int ne = ecnt;
    for (int i = tid; i < ne; i += NTH) {
      int cid = evalids[i];
      float d = dist_p(storage, qf, qn, cid);
      ull key = ((ull)fkey_enc(d) << 32) | (unsigned)cid;
      if (key < kmax) {
        int p = atomicAdd(&cnt, 1);
        keys[p] = key;
      }
    }
    __syncthreads();

    int count = cnt;
    if (count == EFS) break;   // beam unchanged & all its nbrs visited: done

    int m = EFS;
    while (m < count) m <<= 1;
    for (int i = count + tid; i < m; i += NTH) keys[i] = PADKEY;
    __syncthreads();

    bitonic_sort(keys, m, tid);

    if (!dupflag) {
      // all keys distinct: beam = first EFS sorted keys, skip dedup scan
      if (tid < EFS) {
        ull kk = keys[tid];
        beamkey[tid] = kk;
        beam_id[tid] = (int)(kk & 0xFFFFFFFFull);
      }
      __syncthreads();
    } else {
      dedup_compact(keys, m, beamkey, beam_id, scanpart, tid);
    }
  }

  // ---- final: full 128-dim distances, top-k by (d_full, beam position) ----
  if (tid < EFS) {
    int id = beam_id[tid];
    int c = id < 0 ? 0 : (id > N_PTS - 1 ? N_PTS - 1 : id);
    const float4* row = (const float4*)(storage + (size_t)c * DM);
    float acc = 0.f;
#pragma unroll
    for (int j = 0; j < DM / 4; ++j) {
      float4 s = row[j];
      float dx = s.x - qf[4*j+0]; acc = fmaf(dx, dx, acc);
      dx = s.y - qf[4*j+1]; acc = fmaf(dx, dx, acc);
      dx = s.z - qf[4*j+2]; acc = fmaf(dx, dx, acc);
      dx = s.w - qf[4*j+3]; acc = fmaf(dx, dx, acc);
    }
    float dv = (id >= N_PTS) ? BIGF : acc;
    dfull[tid] = dv;
    keys[tid] = ((ull)fkey_enc(dv) << 32) | (unsigned)tid;  // tie-break: position
  }
  __syncthreads();
  bitonic_sort(keys, EFS, tid);
  if (tid < KOUT) {
    int pos = (int)(keys[tid] & 0xFFFFFFFFull);
    out[(size_t)b * KOUT + tid] = (float)beam_id[pos];
    out[(size_t)B * KOUT + (size_t)b * KOUT + tid] = dfull[pos];
  }
}

extern "C" void kernel_launch(void* const* d_in, const int* in_sizes, int n_in,
                              void* d_out, int out_size, void* d_ws, size_t ws_size,
                              hipStream_t stream) {
  const float* query     = (const float*)d_in[0];
  const float* VT        = (const float*)d_in[1];
  const float* storage   = (const float*)d_in[2];
  const int*   neighbors = (const int*)d_in[3];
  const int*   entry_ids = (const int*)d_in[4];
  float* out = (float*)d_out;

  int B = in_sizes[0] / DM;  // 128
  search_kernel<<<B, NTH, 0, stream>>>(query, VT, storage, neighbors, entry_ids, out);
}

// Round 3
// 112.835 us; speedup vs baseline: 1.9509x; 1.5841x over previous
//
#include <hip/hip_runtime.h>

typedef unsigned long long ull;

#define N_PTS   1000000
#define DM      128
#define DP      64
#define RNB     32
#define ENT     32
#define EFS     64
#define KOUT    10
#define N_ITERS 8
#define NTH     512
#define NWAVE   (NTH / 64)
#define HASHCAP 32768
#define MAXNEW  2112
#define BIGF    1e30f
#define PADKEY  0xFFFFFFFFFFFFFFFFull

__device__ __forceinline__ unsigned fkey_enc(float d) {
  unsigned b = __float_as_uint(d);
  return (b & 0x80000000u) ? ~b : (b | 0x80000000u);
}

// Distance in principal subspace (first 64 dims). Fixed accumulation order;
// BIT-IDENTICAL to rounds 0-2 (absmax was 0.0). Do not perturb.
__device__ __forceinline__ float dist_p(const float* __restrict__ storage,
                                        const float* qf, float qn, int id) {
  int c = id < 0 ? 0 : (id > N_PTS - 1 ? N_PTS - 1 : id);
  const float4* row = (const float4*)(storage + (size_t)c * DM);
  float sq = 0.f, dt = 0.f;
#pragma unroll
  for (int j = 0; j < DP / 4; ++j) {
    float4 s = row[j];
    sq = fmaf(s.x, s.x, sq); sq = fmaf(s.y, s.y, sq);
    sq = fmaf(s.z, s.z, sq); sq = fmaf(s.w, s.w, sq);
    dt = fmaf(s.x, qf[4*j+0], dt); dt = fmaf(s.y, qf[4*j+1], dt);
    dt = fmaf(s.z, qf[4*j+2], dt); dt = fmaf(s.w, qf[4*j+3], dt);
  }
  float d = sq - 2.f * dt + qn;
  return (id >= N_PTS) ? BIGF : d;
}

// Visited-set claim. true => caller evaluates (newly claimed).
// Capacity 32768 > hard insert bound (32 + 8*2048 = 16416): always terminates.
__device__ __forceinline__ bool visit_claim(int* htab, int id) {
  unsigned h = ((unsigned)id * 2654435761u) & (HASHCAP - 1);
  while (true) {
    int cur = htab[h];
    if (cur == id) return false;
    if (cur == -1) {
      int old = atomicCAS(&htab[h], -1, id);
      if (old == -1) return true;
      if (old == id) return false;
    }
    h = (h + 1) & (HASHCAP - 1);
  }
}

// Full bitonic sort of 64 keys held one-per-lane in a wave. Ascending. 21 steps.
__device__ __forceinline__ ull wsort64(ull key, int lane) {
#pragma unroll
  for (int k = 2; k <= 64; k <<= 1) {
#pragma unroll
    for (int j = k >> 1; j > 0; j >>= 1) {
      ull other = __shfl_xor(key, j);
      bool up = ((lane & k) == 0);
      bool lower = ((lane & j) == 0);
      ull mn = key < other ? key : other;
      ull mx = key < other ? other : key;
      key = (up == lower) ? mn : mx;
    }
  }
  return key;
}

// Bitonic 64-seq (one per lane) -> ascending. 6 steps.
__device__ __forceinline__ ull wbmerge64(ull key, int lane) {
#pragma unroll
  for (int j = 32; j > 0; j >>= 1) {
    ull other = __shfl_xor(key, j);
    bool lower = ((lane & j) == 0);
    ull mn = key < other ? key : other;
    ull mx = key < other ? other : key;
    key = lower ? mn : mx;
  }
  return key;
}

// Two ascending sorted 64-seqs -> ascending sorted 64 smallest of the union.
__device__ __forceinline__ ull wmerge(ull a, ull b, int lane) {
  ull brev = __shfl_xor(b, 63);           // b reversed: descending
  ull c = a < brev ? a : brev;            // 64 smallest, bitonic
  return wbmerge64(c, lane);
}

__global__ __launch_bounds__(NTH) void search_kernel(
    const float* __restrict__ query,     // B x 128
    const float* __restrict__ VT,        // 128 x 128
    const float* __restrict__ storage,   // N x 128
    const int*   __restrict__ neighbors, // N x 32
    const int*   __restrict__ entry_ids, // 32
    float* __restrict__ out)             // [B*K ids | B*K dists] as float32
{
  __shared__ int   htab[HASHCAP];      // 128 KB
  __shared__ ull   newkeys[MAXNEW];    // 16.5 KB
  __shared__ ull   wavetop[NWAVE + 4][64]; // 6 KB
  __shared__ ull   beamkey[EFS];
  __shared__ int   beam_id[EFS];
  __shared__ float qf[DM];
  __shared__ float qloc[DM];
  __shared__ float qn_s;
  __shared__ int   nc;
  __shared__ float dfull[EFS];

  const int b    = blockIdx.x;
  const int B    = gridDim.x;
  const int tid  = threadIdx.x;
  const int lane = tid & 63;
  const int wid  = tid >> 6;

  const ull FILLKEY = ((ull)fkey_enc(BIGF) << 32) | (unsigned)N_PTS;

  // ---- init visited set ----
  for (int i = tid; i < HASHCAP; i += NTH) htab[i] = -1;

  // ---- q_full = query[b] @ VT.T ----
  if (tid < DM) qloc[tid] = query[(size_t)b * DM + tid];
  __syncthreads();
  if (tid < DM) {
    const float* vrow = VT + (size_t)tid * DM;
    float acc = 0.f;
#pragma unroll 8
    for (int d = 0; d < DM; ++d) acc = fmaf(qloc[d], vrow[d], acc);
    qf[tid] = acc;
  }
  __syncthreads();
  if (tid == 0) {
    float acc = 0.f;
    for (int d = 0; d < DP; ++d) acc = fmaf(qf[d], qf[d], acc);
    qn_s = acc;
  }
  __syncthreads();
  const float qn = qn_s;

  // ---- entry stage: wave 0 only, shuffle sort, no LDS sort ----
  if (wid == 0) {
    ull ek = PADKEY;
    if (lane < ENT) {
      int id = entry_ids[lane];
      if (visit_claim(htab, id)) {           // dedups duplicate entry ids
        float d = dist_p(storage, qf, qn, id);
        ek = ((ull)fkey_enc(d) << 32) | (unsigned)id;
      }
    }
    ek = wsort64(ek, lane);
    if (ek == PADKEY) ek = FILLKEY;
    beamkey[lane] = ek;
    beam_id[lane] = (int)(ek & 0xFFFFFFFFull);
  }
  __syncthreads();

  // ---- search iterations ----
  for (int it = 0; it < N_ITERS; ++it) {
    ull kmax = beamkey[EFS - 1];
    if (tid == 0) nc = 0;
    __syncthreads();

    // fused propose + claim + evaluate + kmax-filter
    for (int ci = tid; ci < EFS * RNB; ci += NTH) {
      int e = ci >> 5;
      int r = ci & 31;
      int bid = beam_id[e];
      if (bid >= N_PTS) continue;            // fill slot (iter 0 only)
      int cid = neighbors[(size_t)bid * RNB + r];
      if (!visit_claim(htab, cid)) continue; // exact skip: key >= kmax
      float d = dist_p(storage, qf, qn, cid);
      ull key = ((ull)fkey_enc(d) << 32) | (unsigned)cid;
      if (key < kmax) {
        int p = atomicAdd(&nc, 1);
        newkeys[p] = key;
      }
    }
    __syncthreads();

    int cnt = nc;
    if (cnt == 0) break;                     // beam fixed: exact early exit

    // per-wave top-64 over candidate chunks (registers + shuffles only)
    ull t = PADKEY;
    int nchunks = (cnt + 63) >> 6;
    for (int c = wid; c < nchunks; c += NWAVE) {
      int idx = (c << 6) + lane;
      ull v = (idx < cnt) ? newkeys[idx] : PADKEY;
      v = wsort64(v, lane);
      t = wmerge(t, v, lane);
    }
    wavetop[wid][lane] = t;
    __syncthreads();

    // tree merge: 8 -> 4 (waves 0-3), then 4 -> 1 + beam merge (wave 0)
    if (wid < 4) {
      ull a = wavetop[2 * wid][lane];
      ull bb = wavetop[2 * wid + 1][lane];
      wavetop[NWAVE + wid][lane] = wmerge(a, bb, lane);
    }
    __syncthreads();
    if (wid == 0) {
      ull m0 = wmerge(wavetop[NWAVE + 0][lane], wavetop[NWAVE + 1][lane], lane);
      ull m1 = wmerge(wavetop[NWAVE + 2][lane], wavetop[NWAVE + 3][lane], lane);
      ull t2 = wmerge(m0, m1, lane);
      ull nb = wmerge(beamkey[lane], t2, lane);   // distinct by construction
      beamkey[lane] = nb;
      beam_id[lane] = (int)(nb & 0xFFFFFFFFull);
    }
    __syncthreads();
  }

  // ---- final: full 128-dim distances + top-k, wave 0 shuffle sort ----
  if (wid == 0) {
    int id = beam_id[lane];
    int c = id < 0 ? 0 : (id > N_PTS - 1 ? N_PTS - 1 : id);
    const float4* row = (const float4*)(storage + (size_t)c * DM);
    float acc = 0.f;
#pragma unroll
    for (int j = 0; j < DM / 4; ++j) {
      float4 s = row[j];
      float dx = s.x - qf[4*j+0]; acc = fmaf(dx, dx, acc);
      dx = s.y - qf[4*j+1]; acc = fmaf(dx, dx, acc);
      dx = s.z - qf[4*j+2]; acc = fmaf(dx, dx, acc);
      dx = s.w - qf[4*j+3]; acc = fmaf(dx, dx, acc);
    }
    float dv = (id >= N_PTS) ? BIGF : acc;
    dfull[lane] = dv;
    ull fk = ((ull)fkey_enc(dv) << 32) | (unsigned)lane;  // tie-break: position
    fk = wsort64(fk, lane);
    if (lane < KOUT) {
      int pos = (int)(fk & 0xFFFFFFFFull);
      out[(size_t)b * KOUT + lane] = (float)beam_id[pos];
      out[(size_t)B * KOUT + (size_t)b * KOUT + lane] = dfull[pos];
    }
  }
}

extern "C" void kernel_launch(void* const* d_in, const int* in_sizes, int n_in,
                              void* d_out, int out_size, void* d_ws, size_t ws_size,
                              hipStream_t stream) {
  const float* query     = (const float*)d_in[0];
  const float* VT        = (const float*)d_in[1];
  const float* storage   = (const float*)d_in[2];
  const int*   neighbors = (const int*)d_in[3];
  const int*   entry_ids = (const int*)d_in[4];
  float* out = (float*)d_out;

  int B = in_sizes[0] / DM;  // 128
  search_kernel<<<B, NTH, 0, stream>>>(query, VT, storage, neighbors, entry_ids, out);
}